// Round 6
// baseline (1011.887 us; speedup 1.0000x reference)
//
#include <hip/hip_runtime.h>
#include <math.h>

#define H 8
#define D 32
// MESSAGE_DIM = H*D = 256

typedef float f32x4 __attribute__((ext_vector_type(4)));

__device__ __forceinline__ float dot4(f32x4 a, f32x4 b) {
    return a.x * b.x + a.y * b.y + a.z * b.z + a.w * b.w;
}

__global__ void aew_init_kernel(float* __restrict__ s, int n) {
    int i = blockIdx.x * blockDim.x + threadIdx.x;
    if (i < n) s[i] = 0.0f;
}

// Pass 1: WAVE-PER-EDGE-PAIR (grid-stride). lane = h*8 + j covers chunk
// [h*32 + j*4 .. +3] of each edge row. Per iteration a wave handles edges
// (2p, 2p+1): one int2 target load (prefetched one iteration ahead to break
// the serial target->gather chain), 2KB contiguous nt message load, two
// independent x_e gather/dot/shuffle chains for 2x MLP. R5 showed the
// single-edge version was latency-bound (~510us vs ~290us BW floor).
// Softmax max-pass dropped (shift-invariant; scores bounded ~|7|).
__global__ __launch_bounds__(256) void aew_score_kernel(
    const int*   __restrict__ target,
    const float* __restrict__ message,
    const float* __restrict__ x_e,
    const float* __restrict__ weight,
    float*       __restrict__ ex,
    float*       __restrict__ s,
    int E)
{
    const int lane = threadIdx.x & 63;
    const int h = lane >> 3;   // head 0..7
    const int j = lane & 7;    // float4 chunk within head
    const int wavesPerBlock = blockDim.x >> 6;
    const int wave = blockIdx.x * wavesPerBlock + (threadIdx.x >> 6);
    const int nWaves = gridDim.x * wavesPerBlock;

    // per-lane weight fragment: w1 = weight[h][j*4..], w2 = weight[h][32+j*4..]
    const f32x4 w1 = *(const f32x4*)(weight + h * 64 + j * 4);
    const f32x4 w2 = *(const f32x4*)(weight + h * 64 + 32 + j * 4);

    const int Epairs = E >> 1;

    int p = wave;
    int2 tt = (p < Epairs) ? *(const int2*)(target + (size_t)2 * p) : make_int2(0, 0);
    for (; p < Epairs; p += nWaves) {
        // prefetch next pair's targets (breaks target->x_e serial chain)
        const int pn = p + nWaves;
        int2 ttn = (pn < Epairs) ? *(const int2*)(target + (size_t)2 * pn) : make_int2(0, 0);

        const size_t e0 = (size_t)2 * p;
        // message: streaming; each line fully consumed by one wave instr -> nt
        // is safe and spares L2/L3 for x_e.
        const f32x4* mrow = (const f32x4*)(message + e0 * 256);
        f32x4 mv0 = __builtin_nontemporal_load(mrow + lane);
        f32x4 mv1 = __builtin_nontemporal_load(mrow + 64 + lane);
        f32x4 xv0 = *((const f32x4*)(x_e + (size_t)tt.x * 256) + lane);
        f32x4 xv1 = *((const f32x4*)(x_e + (size_t)tt.y * 256) + lane);

        float p0 = dot4(mv0, w1) + dot4(xv0, w2);
        float p1 = dot4(mv1, w1) + dot4(xv1, w2);
        // two independent 8-lane reductions, interleaved for ILP
        p0 += __shfl_xor(p0, 1);  p1 += __shfl_xor(p1, 1);
        p0 += __shfl_xor(p0, 2);  p1 += __shfl_xor(p1, 2);
        p0 += __shfl_xor(p0, 4);  p1 += __shfl_xor(p1, 4);
        float a0 = (p0 >= 0.0f) ? p0 : 0.1f * p0;  // LeakyReLU(0.1)
        float a1 = (p1 >= 0.0f) ? p1 : 0.1f * p1;
        float ea0 = __expf(a0);
        float ea1 = __expf(a1);
        if (j == 0) {
            ex[e0 * H + h]     = ea0;
            ex[e0 * H + H + h] = ea1;
            atomicAdd(&s[(size_t)tt.x * H + h], ea0);
            atomicAdd(&s[(size_t)tt.y * H + h], ea1);
        }
        tt = ttn;
    }

    // tail (odd E): handled by wave 0
    if ((E & 1) && wave == 0) {
        const size_t e = (size_t)E - 1;
        int t = target[e];
        f32x4 mv = __builtin_nontemporal_load((const f32x4*)(message + e * 256) + lane);
        f32x4 xv = *((const f32x4*)(x_e + (size_t)t * 256) + lane);
        float pp = dot4(mv, w1) + dot4(xv, w2);
        pp += __shfl_xor(pp, 1);
        pp += __shfl_xor(pp, 2);
        pp += __shfl_xor(pp, 4);
        float a = (pp >= 0.0f) ? pp : 0.1f * pp;
        float ea = __expf(a);
        if (j == 0) {
            ex[e * H + h] = ea;
            atomicAdd(&s[(size_t)t * H + h], ea);
        }
    }
}

// Pass 2: flat f32x4 elementwise: out = message * (ex / max(s[target],1e-16)).
// nt is right here: each line fully consumed within one wave load; keeps the
// 3.3 GB stream from evicting ex/s. (R3-R5: ~470 us, near roofline.)
__global__ __launch_bounds__(256) void aew_output_kernel(
    const int*   __restrict__ target,
    const float* __restrict__ message,
    const float* __restrict__ ex,
    const float* __restrict__ s,
    float*       __restrict__ out,
    int n4)
{
    int i4 = blockIdx.x * blockDim.x + threadIdx.x;
    if (i4 >= n4) return;
    int e = i4 >> 6;
    int h = (i4 & 63) >> 3;
    int t = target[e];
    float sc = ex[e * H + h] / fmaxf(s[t * H + h], 1e-16f);
    f32x4 mv = __builtin_nontemporal_load(((const f32x4*)message) + i4);
    f32x4 o = mv * sc;
    __builtin_nontemporal_store(o, ((f32x4*)out) + i4);
}

extern "C" void kernel_launch(void* const* d_in, const int* in_sizes, int n_in,
                              void* d_out, int out_size, void* d_ws, size_t ws_size,
                              hipStream_t stream) {
    // inputs: source(E), target(E), message(E*256), x_e(N*256), weight(8*64)
    const int*   target  = (const int*)d_in[1];
    const float* message = (const float*)d_in[2];
    const float* x_e     = (const float*)d_in[3];
    const float* weight  = (const float*)d_in[4];
    float* out = (float*)d_out;

    const int E = in_sizes[1];
    const int N = in_sizes[3] / 256;
    const int NH = N * H;

    // ws layout: ex (E*H f32) | s (N*H f32)
    float* ex = (float*)d_ws;
    float* s  = ex + (size_t)E * H;

    aew_init_kernel<<<(NH + 255) / 256, 256, 0, stream>>>(s, NH);
    // 2048 blocks x 256 threads = 8192 waves; each wave handles ~E/2/8192 pairs.
    aew_score_kernel<<<2048, 256, 0, stream>>>(target, message, x_e, weight, ex, s, E);
    const int n4 = E * 64;  // E*256/4 f32x4 elements
    aew_output_kernel<<<(n4 + 255) / 256, 256, 0, stream>>>(target, message, ex, s, out, n4);
}

// Round 7
// 869.146 us; speedup vs baseline: 1.1642x; 1.1642x over previous
//
#include <hip/hip_runtime.h>
#include <math.h>

#define H 8
#define D 32
// MESSAGE_DIM = H*D = 256

typedef float f32x4 __attribute__((ext_vector_type(4)));

__device__ __forceinline__ float dot4(f32x4 a, f32x4 b) {
    return a.x * b.x + a.y * b.y + a.z * b.z + a.w * b.w;
}

__global__ void aew_init_kernel(float* __restrict__ s, int n) {
    int i = blockIdx.x * blockDim.x + threadIdx.x;
    if (i < n) s[i] = 0.0f;
}

// Pass 0: xw[n,h] = x_e[n,h,:].w2[h]  — hoists the edge-independent half of
// the score out of the per-edge loop (R6 analysis: the 1KB/edge x_e gather
// stream, 1.6 GB through L3, co-limited the score pass; this cuts the per-edge
// gather to 32B from a 3.2 MB L2-resident table).
// Wave-per-node: lane = h*8+j, coalesced 1KB row load, 3-level shfl reduce.
__global__ __launch_bounds__(256) void aew_xw_kernel(
    const float* __restrict__ x_e,
    const float* __restrict__ weight,
    float*       __restrict__ xw,
    int N)
{
    const int lane = threadIdx.x & 63;
    const int h = lane >> 3;
    const int j = lane & 7;
    const int wavesPerBlock = blockDim.x >> 6;
    const int wave = blockIdx.x * wavesPerBlock + (threadIdx.x >> 6);
    const int nWaves = gridDim.x * wavesPerBlock;

    const f32x4 w2 = *(const f32x4*)(weight + h * 64 + 32 + j * 4);

    for (int n = wave; n < N; n += nWaves) {
        f32x4 xv = *((const f32x4*)(x_e + (size_t)n * 256) + lane);
        float d = dot4(xv, w2);
        d += __shfl_xor(d, 1);
        d += __shfl_xor(d, 2);
        d += __shfl_xor(d, 4);
        if (j == 0) xw[(size_t)n * H + h] = d;
    }
}

// Pass 1: WAVE-PER-EDGE (grid-stride). lane = h*8+j covers message chunk
// [h*32+j*4 .. +3]: one 1KB fully-coalesced nt load per edge. Score =
// dot(m,w1) (3 shfl reduce) + xw[t,h] (32B L2 gather, prefetched one
// iteration ahead). LeakyReLU, exp, write ex, atomicAdd s.
// Softmax max-pass dropped (shift-invariant; scores bounded ~|7|).
__global__ __launch_bounds__(256) void aew_score_kernel(
    const int*   __restrict__ target,
    const float* __restrict__ message,
    const float* __restrict__ xw,
    const float* __restrict__ weight,
    float*       __restrict__ ex,
    float*       __restrict__ s,
    int E)
{
    const int lane = threadIdx.x & 63;
    const int h = lane >> 3;
    const int j = lane & 7;
    const int wavesPerBlock = blockDim.x >> 6;
    const int wave = blockIdx.x * wavesPerBlock + (threadIdx.x >> 6);
    const int nWaves = gridDim.x * wavesPerBlock;

    const f32x4 w1 = *(const f32x4*)(weight + h * 64 + j * 4);

    int e = wave;
    int t = (e < E) ? target[e] : 0;
    float xwv = (e < E) ? xw[(size_t)t * H + h] : 0.0f;
    for (; e < E; e += nWaves) {
        // prefetch next edge's target + xw (breaks the serial addr chain)
        const int en = e + nWaves;
        int tn = (en < E) ? target[en] : 0;
        float xwn = (en < E) ? xw[(size_t)tn * H + h] : 0.0f;

        // message: streaming; each line fully consumed by one wave instr -> nt
        // spares L2/L3 for xw/s tables.
        f32x4 mv = __builtin_nontemporal_load((const f32x4*)(message + (size_t)e * 256) + lane);
        float d = dot4(mv, w1);
        d += __shfl_xor(d, 1);
        d += __shfl_xor(d, 2);
        d += __shfl_xor(d, 4);
        float p = d + xwv;
        float a = (p >= 0.0f) ? p : 0.1f * p;  // LeakyReLU(0.1)
        float ea = __expf(a);
        if (j == 0) {
            ex[(size_t)e * H + h] = ea;
            atomicAdd(&s[(size_t)t * H + h], ea);
        }
        t = tn; xwv = xwn;
    }
}

// Pass 2: flat f32x4 elementwise: out = message * (ex / max(s[target],1e-16)).
// nt is right here: each line fully consumed within one wave load. At its
// mixed read+write roofline (~470us for 3.28 GB HBM) since R3.
__global__ __launch_bounds__(256) void aew_output_kernel(
    const int*   __restrict__ target,
    const float* __restrict__ message,
    const float* __restrict__ ex,
    const float* __restrict__ s,
    float*       __restrict__ out,
    int n4)
{
    int i4 = blockIdx.x * blockDim.x + threadIdx.x;
    if (i4 >= n4) return;
    int e = i4 >> 6;
    int h = (i4 & 63) >> 3;
    int t = target[e];
    float sc = ex[e * H + h] / fmaxf(s[t * H + h], 1e-16f);
    f32x4 mv = __builtin_nontemporal_load(((const f32x4*)message) + i4);
    f32x4 o = mv * sc;
    __builtin_nontemporal_store(o, ((f32x4*)out) + i4);
}

extern "C" void kernel_launch(void* const* d_in, const int* in_sizes, int n_in,
                              void* d_out, int out_size, void* d_ws, size_t ws_size,
                              hipStream_t stream) {
    // inputs: source(E), target(E), message(E*256), x_e(N*256), weight(8*64)
    const int*   target  = (const int*)d_in[1];
    const float* message = (const float*)d_in[2];
    const float* x_e     = (const float*)d_in[3];
    const float* weight  = (const float*)d_in[4];
    float* out = (float*)d_out;

    const int E = in_sizes[1];
    const int N = in_sizes[3] / 256;
    const int NH = N * H;

    // ws layout: ex (E*H f32) | s (N*H f32) | xw (N*H f32)
    float* ex = (float*)d_ws;
    float* s  = ex + (size_t)E * H;
    float* xw = s + (size_t)NH;

    aew_init_kernel<<<(NH + 255) / 256, 256, 0, stream>>>(s, NH);
    aew_xw_kernel<<<1024, 256, 0, stream>>>(x_e, weight, xw, N);
    // 2048 blocks x 256 threads = 8192 waves, grid-stride over E edges.
    aew_score_kernel<<<2048, 256, 0, stream>>>(target, message, xw, weight, ex, s, E);
    const int n4 = E * 64;  // E*256/4 f32x4 elements
    aew_output_kernel<<<(n4 + 255) / 256, 256, 0, stream>>>(target, message, ex, s, out, n4);
}